// Round 6
// baseline (142.815 us; speedup 1.0000x reference)
//
#include <hip/hip_runtime.h>
#include <hip/hip_bf16.h>

#define HEADS  16
#define DIMH   64
#define NBATCH 2
#define SEQ    2048
#define DMODEL 1024
#define MROWS  (NBATCH * SEQ)   // 4096

typedef __attribute__((ext_vector_type(8)))  short bf16x8;
typedef __attribute__((ext_vector_type(4)))  float f32x4;
typedef __attribute__((ext_vector_type(16))) float f32x16;
typedef __attribute__((ext_vector_type(4)))  float float4v;
typedef __attribute__((ext_vector_type(4)))  short short4v;

__device__ inline void glds16(const void* g, void* l) {
    __builtin_amdgcn_global_load_lds(
        (const __attribute__((address_space(1))) unsigned int*)g,
        (__attribute__((address_space(3))) unsigned int*)l, 16, 0, 0);
}

#define WAIT_VMCNT(N) asm volatile("s_waitcnt vmcnt(" #N ")" ::: "memory")
#define BARRIER() do { __builtin_amdgcn_s_barrier(); asm volatile("" ::: "memory"); } while (0)

// ---------------- f32 -> bf16 cast (4 elems/thread) ----------------
__global__ void cvt_kernel(const float* __restrict__ in,
                           __hip_bfloat16* __restrict__ out, int n4) {
    int i = blockIdx.x * blockDim.x + threadIdx.x;
    if (i >= n4) return;
    float4v v = reinterpret_cast<const float4v*>(in)[i];
    union { short4v s; __hip_bfloat16 h[4]; } u;
#pragma unroll
    for (int j = 0; j < 4; ++j) u.h[j] = __float2bfloat16(v[j]);
    reinterpret_cast<short4v*>(out)[i] = u.s;
}

// ------------- W [D][D] f32 -> WT [o][i] bf16 (transpose+cast) -------------
__global__ void tr_kernel(const float* __restrict__ W,
                          __hip_bfloat16* __restrict__ WT) {
    __shared__ float tile[32][33];
    int i = blockIdx.y * 32 + threadIdx.y;   // row of W
    int o = blockIdx.x * 32 + threadIdx.x;   // col of W
    tile[threadIdx.y][threadIdx.x] = W[i * DMODEL + o];
    __syncthreads();
    int oo = blockIdx.x * 32 + threadIdx.y;  // row of WT
    int ii = blockIdx.y * 32 + threadIdx.x;  // col of WT
    WT[oo * DMODEL + ii] = __float2bfloat16(tile[threadIdx.x][threadIdx.y]);
}

// ============ 8-wave GEMM core (BK=32, 3-buffer, counted vmcnt) ============
// A [M][1024] bf16 row-major; B [N][1024] bf16 row-major (C = A @ B^T).
// LDS in FRAGMENT ORDER: frag-block fb (16 rows x 32 k = 1KB) at lds[fb*1024
// + lane*16], lane = (row&15) + 16*kchunk; staged by permuting the per-lane
// GLOBAL source (dest stays linear); all ds_read_b128 are base+lane*16.

// ---------------- fused Q/KV projection GEMM (BM=128, BN=256) --------------
__launch_bounds__(512, 2)
__global__ void proj_kernel(const __hip_bfloat16* __restrict__ hsb,
                            const __hip_bfloat16* __restrict__ WqT,
                            const __hip_bfloat16* __restrict__ WkvT,
                            __hip_bfloat16* __restrict__ qb,
                            __hip_bfloat16* __restrict__ kb,
                            __hip_bfloat16* __restrict__ vtb) {
    __shared__ __align__(16) char Alds[3][8192];    // 128x32 bf16
    __shared__ __align__(16) char Blds[3][16384];   // 256x32 bf16
    const int tid  = threadIdx.x;         // 0..511
    const int wave = tid >> 6;            // 0..7
    const int lane = tid & 63;
    const int lr = lane & 15;
    const int lk = lane >> 4;
    const int wm = wave >> 2, wn = wave & 3;   // 2M x 4N, wave tile 64x64

    // bijective XCD swizzle: 256 blocks, 32 contiguous ids per XCD
    int bid = blockIdx.x;
    bid = (bid & 7) * 32 + (bid >> 3);
    const int xt = bid & 7;               // n-tile of 256 (q: 0..3, kv: 4..7)
    const int mt = bid >> 3;              // m-tile 0..31
    const bool is_q = xt < 4;
    const int mbase = mt * 128;
    const int nbase = (xt & 3) * 256;
    const __hip_bfloat16* __restrict__ WT = is_q ? WqT : WkvT;

    const char* __restrict__ Ab = (const char*)(hsb + (size_t)mbase * DMODEL);
    const char* __restrict__ Bb = (const char*)(WT + (size_t)nbase * DMODEL);

    // staging pattern (per thread, constant): fb0 = wave, row lr, k-chunk lk
    auto stage = [&](int buf, int k0) {
        const size_t colb = (size_t)k0 * 2 + lk * 16;
        glds16(Ab + (size_t)(wave * 16 + lr) * (DMODEL * 2) + colb,
               &Alds[buf][wave * 1024]);
#pragma unroll
        for (int r = 0; r < 2; ++r)
            glds16(Bb + (size_t)((r * 8 + wave) * 16 + lr) * (DMODEL * 2) + colb,
                   &Blds[buf][r * 8192 + wave * 1024]);
    };

    stage(0, 0);
    stage(1, 32);

    f32x4 acc[4][4] = {};
    int c0 = 0;
    for (int t = 0; t < DMODEL / 32; ++t) {
        if (t < DMODEL / 32 - 1) WAIT_VMCNT(3); else WAIT_VMCNT(0);
        BARRIER();
        if (t + 2 < DMODEL / 32) {
            int sb = c0 + 2; if (sb >= 3) sb -= 3;
            stage(sb, (t + 2) * 32);
        }
        bf16x8 af[4], bfr[4];
#pragma unroll
        for (int i = 0; i < 4; ++i) {
            af[i]  = *reinterpret_cast<const bf16x8*>(&Alds[c0][(wm * 4 + i) * 1024 + lane * 16]);
            bfr[i] = *reinterpret_cast<const bf16x8*>(&Blds[c0][(wn * 4 + i) * 1024 + lane * 16]);
        }
#pragma unroll
        for (int i = 0; i < 4; ++i)
#pragma unroll
            for (int j = 0; j < 4; ++j)
                acc[i][j] = __builtin_amdgcn_mfma_f32_16x16x32_bf16(af[i], bfr[j], acc[i][j], 0, 0, 0);
        c0 = (c0 + 1 == 3) ? 0 : c0 + 1;
    }

    const float qscale = is_q ? 0.125f : 1.0f;   // fold attention scale into Q
#pragma unroll
    for (int i = 0; i < 4; ++i) {
#pragma unroll
        for (int j = 0; j < 4; ++j) {
#pragma unroll
            for (int r = 0; r < 4; ++r) {
                int m = mbase + wm * 64 + i * 16 + lk * 4 + r;
                int b_ = m >> 11, s = m & (SEQ - 1);
                int n = nbase + wn * 64 + j * 16 + lr;
                int h = n >> 6, dh = n & 63;
                __hip_bfloat16 hv = __float2bfloat16(acc[i][j][r] * qscale);
                size_t idx = ((size_t)(b_ * HEADS + h) * SEQ + s) * DIMH + dh;
                if (is_q) {
                    qb[idx] = hv;
                } else {
                    kb[idx] = hv;
                    vtb[((size_t)(b_ * HEADS + h) * DIMH + dh) * SEQ + s] = hv;
                }
            }
        }
    }
}

// -------- output projection GEMM + bias (BM=128, BN=128, f32 out) ----------
__launch_bounds__(512, 2)
__global__ void outproj_kernel(const __hip_bfloat16* __restrict__ ao,
                               const __hip_bfloat16* __restrict__ WoT,
                               const float* __restrict__ bout,
                               float* __restrict__ out) {
    __shared__ __align__(16) char Alds[3][8192];
    __shared__ __align__(16) char Blds[3][8192];
    const int tid  = threadIdx.x;
    const int wave = tid >> 6;
    const int lane = tid & 63;
    const int lr = lane & 15;
    const int lk = lane >> 4;
    const int wm = wave >> 1, wn = wave & 1;   // 4M x 2N, wave tile 32x64

    // bijective XCD swizzle: 256 blocks, 32 contiguous ids per XCD
    int bid = blockIdx.x;
    bid = (bid & 7) * 32 + (bid >> 3);
    const int xt = bid & 7;
    const int mt = bid >> 3;
    const int mbase = mt * 128;
    const int nbase = xt * 128;

    const char* __restrict__ Ab = (const char*)(ao + (size_t)mbase * DMODEL);
    const char* __restrict__ Bb = (const char*)(WoT + (size_t)nbase * DMODEL);

    auto stage = [&](int buf, int k0) {
        const size_t colb = (size_t)k0 * 2 + lk * 16;
        glds16(Ab + (size_t)(wave * 16 + lr) * (DMODEL * 2) + colb,
               &Alds[buf][wave * 1024]);
        glds16(Bb + (size_t)(wave * 16 + lr) * (DMODEL * 2) + colb,
               &Blds[buf][wave * 1024]);
    };

    stage(0, 0);
    stage(1, 32);

    f32x4 acc[2][4] = {};
    int c0 = 0;
    for (int t = 0; t < DMODEL / 32; ++t) {
        if (t < DMODEL / 32 - 1) WAIT_VMCNT(2); else WAIT_VMCNT(0);
        BARRIER();
        if (t + 2 < DMODEL / 32) {
            int sb = c0 + 2; if (sb >= 3) sb -= 3;
            stage(sb, (t + 2) * 32);
        }
        bf16x8 af[2], bfr[4];
#pragma unroll
        for (int i = 0; i < 2; ++i)
            af[i] = *reinterpret_cast<const bf16x8*>(&Alds[c0][(wm * 2 + i) * 1024 + lane * 16]);
#pragma unroll
        for (int j = 0; j < 4; ++j)
            bfr[j] = *reinterpret_cast<const bf16x8*>(&Blds[c0][(wn * 4 + j) * 1024 + lane * 16]);
#pragma unroll
        for (int i = 0; i < 2; ++i)
#pragma unroll
            for (int j = 0; j < 4; ++j)
                acc[i][j] = __builtin_amdgcn_mfma_f32_16x16x32_bf16(af[i], bfr[j], acc[i][j], 0, 0, 0);
        c0 = (c0 + 1 == 3) ? 0 : c0 + 1;
    }

#pragma unroll
    for (int j = 0; j < 4; ++j) {
        const int n = nbase + wn * 64 + j * 16 + lr;
        const float bias = bout[n];
#pragma unroll
        for (int i = 0; i < 2; ++i) {
#pragma unroll
            for (int r = 0; r < 4; ++r) {
                int m = mbase + wm * 32 + i * 16 + lk * 4 + r;
                out[(size_t)m * DMODEL + n] = acc[i][j][r] + bias;
            }
        }
    }
}

// ---------------- fused ReLU attention, 32x32 MFMA + LDS-staged K/V ----------------
__launch_bounds__(256, 2)
__global__ void attn_kernel(const __hip_bfloat16* __restrict__ qb,
                            const __hip_bfloat16* __restrict__ kb,
                            const __hip_bfloat16* __restrict__ vtb,
                            __hip_bfloat16* __restrict__ ao) {
    __shared__ __align__(16) char Klds[3][8192];
    __shared__ __align__(16) char Vlds[3][8192];
    const int lane = threadIdx.x & 63;
    const int wave = threadIdx.x >> 6;
    const int l32  = lane & 31;
    const int hi   = lane >> 5;

    int bid = blockIdx.x;
    bid = (bid & 7) * 64 + (bid >> 3);
    const int bh   = bid >> 4;            // 0..31  (= b*16 + h)
    const int qblk = bid & 15;            // 0..15
    const int b_ = bh >> 4, h = bh & 15;
    const int qbase = qblk * 128 + wave * 32;

    const __hip_bfloat16* __restrict__ Q = qb + (size_t)bh * SEQ * DIMH;
    const char* __restrict__ Kg = (const char*)(kb  + (size_t)bh * SEQ * DIMH);
    const char* __restrict__ Vg = (const char*)(vtb + (size_t)bh * DIMH * SEQ);

    bf16x8 qf[4];
#pragma unroll
    for (int ks = 0; ks < 4; ++ks)
        qf[ks] = *reinterpret_cast<const bf16x8*>(
            &Q[(size_t)(qbase + l32) * DIMH + ks * 16 + hi * 8]);

    f32x16 acco[2] = {};

    auto stage = [&](int buf, int t0) {
#pragma unroll
        for (int pass = 0; pass < 2; ++pass) {
            const int b   = wave * 2048 + pass * 1024 + lane * 16;
            const int row = b >> 7;
            const int cb  = (b & 127) ^ ((row & 7) << 4);
            glds16(Kg + (size_t)(t0 + row) * 128 + cb,
                   &Klds[buf][wave * 2048 + pass * 1024]);
            glds16(Vg + (size_t)row * (SEQ * 2) + t0 * 2 + cb,
                   &Vlds[buf][wave * 2048 + pass * 1024]);
        }
    };

    stage(0, 0);
    stage(1, 64);

    const int swz = (l32 & 7) << 4;
    int c0 = 0;
    for (int t0 = 0; t0 < SEQ; t0 += 64) {
        if (t0 + 64 < SEQ) WAIT_VMCNT(4); else WAIT_VMCNT(0);
        BARRIER();
        if (t0 + 128 < SEQ) {
            int sb = c0 + 2; if (sb >= 3) sb -= 3;
            stage(sb, t0 + 128);
        }
        const char* Kc = Klds[c0];
        const char* Vc = Vlds[c0];

        // ---- S^T = K Q^T ----
        f32x16 s0 = {}, s1 = {};
#pragma unroll
        for (int ks = 0; ks < 4; ++ks) {
            bf16x8 k0f = *reinterpret_cast<const bf16x8*>(
                Kc + l32 * 128        + ((ks * 32 + 16 * hi) ^ swz));
            bf16x8 k1f = *reinterpret_cast<const bf16x8*>(
                Kc + (32 + l32) * 128 + ((ks * 32 + 16 * hi) ^ swz));
            s0 = __builtin_amdgcn_mfma_f32_32x32x16_bf16(k0f, qf[ks], s0, 0, 0, 0);
            s1 = __builtin_amdgcn_mfma_f32_32x32x16_bf16(k1f, qf[ks], s1, 0, 0, 0);
        }
#pragma unroll
        for (int r = 0; r < 16; ++r) {
            s0[r] = fmaxf(s0[r], 0.f);
            s1[r] = fmaxf(s1[r], 0.f);
        }
        // ---- O += P V (lane-local P; scrambled-t V reads) ----
#pragma unroll
        for (int kt = 0; kt < 4; ++kt) {
            union { __hip_bfloat16 hh[8]; bf16x8 v; } pa;
            const int rb = (kt & 1) * 8;
#pragma unroll
            for (int j = 0; j < 8; ++j)
                pa.hh[j] = __float2bfloat16(kt < 2 ? s0[rb + j] : s1[rb + j]);
#pragma unroll
            for (int nt = 0; nt < 2; ++nt) {
                const int row = nt * 32 + l32;
                union { unsigned long long d[2]; bf16x8 v; } vb;
                vb.d[0] = *reinterpret_cast<const unsigned long long*>(
                    Vc + row * 128 + ((kt * 32 + 8 * hi) ^ swz));
                vb.d[1] = *reinterpret_cast<const unsigned long long*>(
                    Vc + row * 128 + ((kt * 32 + 16 + 8 * hi) ^ swz));
                acco[nt] = __builtin_amdgcn_mfma_f32_32x32x16_bf16(pa.v, vb.v, acco[nt], 0, 0, 0);
            }
        }
        c0 = (c0 + 1 == 3) ? 0 : c0 + 1;
    }

#pragma unroll
    for (int nt = 0; nt < 2; ++nt) {
#pragma unroll
        for (int r = 0; r < 16; ++r) {
            int q = qbase + (r & 3) + 8 * (r >> 2) + 4 * hi;
            ao[(size_t)(b_ * SEQ + q) * DMODEL + h * 64 + nt * 32 + l32] =
                __float2bfloat16(acco[nt][r]);
        }
    }
}

extern "C" void kernel_launch(void* const* d_in, const int* in_sizes, int n_in,
                              void* d_out, int out_size, void* d_ws, size_t ws_size,
                              hipStream_t stream) {
    const float* hs   = (const float*)d_in[0];
    const float* Wq   = (const float*)d_in[1];
    const float* Wkv  = (const float*)d_in[2];
    const float* Wout = (const float*)d_in[3];
    const float* bout = (const float*)d_in[4];
    float* out = (float*)d_out;

    char* ws = (char*)d_ws;
    size_t off = 0;
    auto alloc = [&](size_t bytes) { char* p = ws + off; off += bytes; return p; };
    __hip_bfloat16* hsb  = (__hip_bfloat16*)alloc((size_t)MROWS * DMODEL * 2); // dead after proj
    __hip_bfloat16* WqT  = (__hip_bfloat16*)alloc((size_t)DMODEL * DMODEL * 2);
    __hip_bfloat16* WkvT = (__hip_bfloat16*)alloc((size_t)DMODEL * DMODEL * 2);
    __hip_bfloat16* WoT  = (__hip_bfloat16*)alloc((size_t)DMODEL * DMODEL * 2);
    __hip_bfloat16* qb   = (__hip_bfloat16*)alloc((size_t)MROWS * DMODEL * 2);
    __hip_bfloat16* kb   = (__hip_bfloat16*)alloc((size_t)MROWS * DMODEL * 2);
    __hip_bfloat16* vtb  = (__hip_bfloat16*)alloc((size_t)MROWS * DMODEL * 2);
    __hip_bfloat16* ao   = hsb;  // alias: hs_bf16 is dead once attention runs

    // 1. casts / transposes
    cvt_kernel<<<(MROWS * DMODEL / 4 + 255) / 256, 256, 0, stream>>>(hs, hsb, MROWS * DMODEL / 4);
    dim3 trg(32, 32), trb(32, 32);
    tr_kernel<<<trg, trb, 0, stream>>>(Wq, WqT);
    tr_kernel<<<trg, trb, 0, stream>>>(Wkv, WkvT);
    tr_kernel<<<trg, trb, 0, stream>>>(Wout, WoT);

    // 2. fused Q/KV projection (Q pre-scaled by 1/8): 256 blocks x 512 thr
    proj_kernel<<<256, 512, 0, stream>>>(hsb, WqT, WkvT, qb, kb, vtb);

    // 3. fused relu attention
    attn_kernel<<<NBATCH * HEADS * (SEQ / 128), 256, 0, stream>>>(qb, kb, vtb, ao);

    // 4. output projection: 256 blocks x 512 thr
    outproj_kernel<<<256, 512, 0, stream>>>(ao, WoT, bout, out);
}

// Round 7
// 120.640 us; speedup vs baseline: 1.1838x; 1.1838x over previous
//
#include <hip/hip_runtime.h>
#include <hip/hip_bf16.h>

#define HEADS  16
#define DIMH   64
#define NBATCH 2
#define SEQ    2048
#define DMODEL 1024
#define MROWS  (NBATCH * SEQ)   // 4096

typedef __attribute__((ext_vector_type(8)))  short bf16x8;
typedef __attribute__((ext_vector_type(4)))  float f32x4;
typedef __attribute__((ext_vector_type(16))) float f32x16;
typedef __attribute__((ext_vector_type(4)))  float float4v;
typedef __attribute__((ext_vector_type(4)))  short short4v;

__device__ inline void glds16(const void* g, void* l) {
    __builtin_amdgcn_global_load_lds(
        (const __attribute__((address_space(1))) unsigned int*)g,
        (__attribute__((address_space(3))) unsigned int*)l, 16, 0, 0);
}

#define WAIT_VMCNT(N) asm volatile("s_waitcnt vmcnt(" #N ")" ::: "memory")
#define BARRIER() do { __builtin_amdgcn_s_barrier(); asm volatile("" ::: "memory"); } while (0)

// ---------------- f32 -> bf16 cast (4 elems/thread) ----------------
__global__ void cvt_kernel(const float* __restrict__ in,
                           __hip_bfloat16* __restrict__ out, int n4) {
    int i = blockIdx.x * blockDim.x + threadIdx.x;
    if (i >= n4) return;
    float4v v = reinterpret_cast<const float4v*>(in)[i];
    union { short4v s; __hip_bfloat16 h[4]; } u;
#pragma unroll
    for (int j = 0; j < 4; ++j) u.h[j] = __float2bfloat16(v[j]);
    reinterpret_cast<short4v*>(out)[i] = u.s;
}

// ------------- W [D][D] f32 -> WT [o][i] bf16 (transpose+cast) -------------
__global__ void tr_kernel(const float* __restrict__ W,
                          __hip_bfloat16* __restrict__ WT) {
    __shared__ float tile[32][33];
    int i = blockIdx.y * 32 + threadIdx.y;   // row of W
    int o = blockIdx.x * 32 + threadIdx.x;   // col of W
    tile[threadIdx.y][threadIdx.x] = W[i * DMODEL + o];
    __syncthreads();
    int oo = blockIdx.x * 32 + threadIdx.y;  // row of WT
    int ii = blockIdx.y * 32 + threadIdx.x;  // col of WT
    WT[oo * DMODEL + ii] = __float2bfloat16(tile[threadIdx.x][threadIdx.y]);
}

// ============ 8-wave GEMM core (BK=32, 3-buffer, counted vmcnt) ============
// A [M][1024] bf16 row-major; B [N][1024] bf16 row-major (C = A @ B^T).
// LDS in FRAGMENT ORDER: frag-block fb (16 rows x 32 k = 1KB) at lds[fb*1024
// + lane*16]; staged by permuting the per-lane GLOBAL source (dest linear).
// Epilogue goes through LDS (reusing staging space) for coalesced stores.

// ---------------- fused Q/KV projection GEMM (BM=128, BN=256) --------------
__launch_bounds__(512, 2)
__global__ void proj_kernel(const __hip_bfloat16* __restrict__ hsb,
                            const __hip_bfloat16* __restrict__ WqT,
                            const __hip_bfloat16* __restrict__ WkvT,
                            __hip_bfloat16* __restrict__ qb,
                            __hip_bfloat16* __restrict__ kb,
                            __hip_bfloat16* __restrict__ vtb) {
    __shared__ __align__(16) char SLDS[73728];
    char (*Alds)[8192]  = (char (*)[8192])SLDS;              // 3 x 8KB
    char (*Blds)[16384] = (char (*)[16384])(SLDS + 24576);   // 3 x 16KB
    char* CT = SLDS;                                         // 64KB reuse

    const int tid  = threadIdx.x;         // 0..511
    const int wave = tid >> 6;            // 0..7
    const int lane = tid & 63;
    const int lr = lane & 15;
    const int lk = lane >> 4;
    const int wm = wave >> 2, wn = wave & 3;   // 2M x 4N, wave tile 64x64

    // bijective XCD swizzle: 256 blocks, 32 contiguous ids per XCD
    int bid = blockIdx.x;
    bid = (bid & 7) * 32 + (bid >> 3);
    const int xt = bid & 7;               // n-tile of 256 (q: 0..3, kv: 4..7)
    const int mt = bid >> 3;              // m-tile 0..31
    const bool is_q = xt < 4;
    const int mbase = mt * 128;
    const int nbase = (xt & 3) * 256;
    const __hip_bfloat16* __restrict__ WT = is_q ? WqT : WkvT;

    const char* __restrict__ Ab = (const char*)(hsb + (size_t)mbase * DMODEL);
    const char* __restrict__ Bb = (const char*)(WT + (size_t)nbase * DMODEL);

    auto stage = [&](int buf, int k0) {
        const size_t colb = (size_t)k0 * 2 + lk * 16;
        glds16(Ab + (size_t)(wave * 16 + lr) * (DMODEL * 2) + colb,
               &Alds[buf][wave * 1024]);
#pragma unroll
        for (int r = 0; r < 2; ++r)
            glds16(Bb + (size_t)((r * 8 + wave) * 16 + lr) * (DMODEL * 2) + colb,
                   &Blds[buf][r * 8192 + wave * 1024]);
    };

    stage(0, 0);
    stage(1, 32);

    f32x4 acc[4][4] = {};
    int c0 = 0;
    for (int t = 0; t < DMODEL / 32; ++t) {
        if (t < DMODEL / 32 - 1) WAIT_VMCNT(3); else WAIT_VMCNT(0);
        BARRIER();
        if (t + 2 < DMODEL / 32) {
            int sb = c0 + 2; if (sb >= 3) sb -= 3;
            stage(sb, (t + 2) * 32);
        }
        bf16x8 af[4], bfr[4];
#pragma unroll
        for (int i = 0; i < 4; ++i) {
            af[i]  = *reinterpret_cast<const bf16x8*>(&Alds[c0][(wm * 4 + i) * 1024 + lane * 16]);
            bfr[i] = *reinterpret_cast<const bf16x8*>(&Blds[c0][(wn * 4 + i) * 1024 + lane * 16]);
        }
#pragma unroll
        for (int i = 0; i < 4; ++i)
#pragma unroll
            for (int j = 0; j < 4; ++j)
                acc[i][j] = __builtin_amdgcn_mfma_f32_16x16x32_bf16(af[i], bfr[j], acc[i][j], 0, 0, 0);
        c0 = (c0 + 1 == 3) ? 0 : c0 + 1;
    }

    // ================= epilogue via LDS (coalesced stores) =================
    const float qscale = is_q ? 0.125f : 1.0f;   // fold attention scale into Q
    const int b_ = mbase >> 11;
    const int s0 = mbase & (SEQ - 1);
    BARRIER();   // all waves done reading staging LDS

    // 1) acc -> CT [128m][256n] bf16, key = ((m>>2)&7)<<4
#pragma unroll
    for (int i = 0; i < 4; ++i)
#pragma unroll
        for (int j = 0; j < 4; ++j)
#pragma unroll
            for (int r = 0; r < 4; ++r) {
                int m = wm * 64 + i * 16 + lk * 4 + r;
                int n = wn * 64 + j * 16 + lr;
                *reinterpret_cast<__hip_bfloat16*>(
                    &CT[m * 512 + ((n * 2) ^ (((m >> 2) & 7) << 4))]) =
                    __float2bfloat16(acc[i][j][r] * qscale);
            }
    BARRIER();

    // 2) coalesced q/k stores: 8-lane groups write 128B head-segment runs
    __hip_bfloat16* __restrict__ dst0 = is_q ? qb : kb;
#pragma unroll
    for (int p = 0; p < 8; ++p) {
        int g = p * 64 + (tid >> 3);      // 0..511
        int m = g >> 2, seg = g & 3, o = tid & 7;
        int key = ((m >> 2) & 7) << 4;
        bf16x8 val = *reinterpret_cast<const bf16x8*>(
            &CT[m * 512 + ((seg * 128 + o * 16) ^ key)]);
        int h = (nbase >> 6) + seg;
        *reinterpret_cast<bf16x8*>(
            &dst0[(((size_t)b_ * HEADS + h) * SEQ + s0 + m) * DIMH + o * 8]) = val;
    }

    if (!is_q) {
        BARRIER();
        // 3) acc -> CT2 [256n][128m] bf16, key2 = ((n&7)<<4)
#pragma unroll
        for (int i = 0; i < 4; ++i)
#pragma unroll
            for (int j = 0; j < 4; ++j)
#pragma unroll
                for (int r = 0; r < 4; ++r) {
                    int m = wm * 64 + i * 16 + lk * 4 + r;
                    int n = wn * 64 + j * 16 + lr;
                    *reinterpret_cast<__hip_bfloat16*>(
                        &CT[n * 256 + ((m * 2) ^ ((n & 7) << 4))]) =
                        __float2bfloat16(acc[i][j][r]);
                }
        BARRIER();
        // 4) coalesced vtb stores: 8-lane groups write 128B s-runs
#pragma unroll
        for (int p = 0; p < 8; ++p) {
            int g = p * 64 + (tid >> 3);      // 0..511
            int n = g >> 1, half = g & 1, o = tid & 7;
            int key2 = (n & 7) << 4;
            bf16x8 val = *reinterpret_cast<const bf16x8*>(
                &CT[n * 256 + ((half * 128 + o * 16) ^ key2)]);
            int h = (nbase >> 6) + (n >> 6);
            int dh = n & 63;
            *reinterpret_cast<bf16x8*>(
                &vtb[(((size_t)b_ * HEADS + h) * DIMH + dh) * SEQ + s0 + half * 64 + o * 8]) = val;
        }
    }
}

// -------- output projection GEMM + bias (BM=128, BN=128, f32 out) ----------
__launch_bounds__(512, 2)
__global__ void outproj_kernel(const __hip_bfloat16* __restrict__ ao,
                               const __hip_bfloat16* __restrict__ WoT,
                               const float* __restrict__ bout,
                               float* __restrict__ out) {
    __shared__ __align__(16) char Alds[3][8192];
    __shared__ __align__(16) char Blds[3][8192];
    const int tid  = threadIdx.x;
    const int wave = tid >> 6;
    const int lane = tid & 63;
    const int lr = lane & 15;
    const int lk = lane >> 4;
    const int wm = wave >> 1, wn = wave & 1;   // 4M x 2N, wave tile 32x64

    // bijective XCD swizzle: 256 blocks, 32 contiguous ids per XCD
    int bid = blockIdx.x;
    bid = (bid & 7) * 32 + (bid >> 3);
    const int xt = bid & 7;
    const int mt = bid >> 3;
    const int mbase = mt * 128;
    const int nbase = xt * 128;

    const char* __restrict__ Ab = (const char*)(ao + (size_t)mbase * DMODEL);
    const char* __restrict__ Bb = (const char*)(WoT + (size_t)nbase * DMODEL);

    auto stage = [&](int buf, int k0) {
        const size_t colb = (size_t)k0 * 2 + lk * 16;
        glds16(Ab + (size_t)(wave * 16 + lr) * (DMODEL * 2) + colb,
               &Alds[buf][wave * 1024]);
        glds16(Bb + (size_t)(wave * 16 + lr) * (DMODEL * 2) + colb,
               &Blds[buf][wave * 1024]);
    };

    stage(0, 0);
    stage(1, 32);

    f32x4 acc[2][4] = {};
    int c0 = 0;
    for (int t = 0; t < DMODEL / 32; ++t) {
        if (t < DMODEL / 32 - 1) WAIT_VMCNT(2); else WAIT_VMCNT(0);
        BARRIER();
        if (t + 2 < DMODEL / 32) {
            int sb = c0 + 2; if (sb >= 3) sb -= 3;
            stage(sb, (t + 2) * 32);
        }
        bf16x8 af[2], bfr[4];
#pragma unroll
        for (int i = 0; i < 2; ++i)
            af[i] = *reinterpret_cast<const bf16x8*>(&Alds[c0][(wm * 2 + i) * 1024 + lane * 16]);
#pragma unroll
        for (int j = 0; j < 4; ++j)
            bfr[j] = *reinterpret_cast<const bf16x8*>(&Blds[c0][(wn * 4 + j) * 1024 + lane * 16]);
#pragma unroll
        for (int i = 0; i < 2; ++i)
#pragma unroll
            for (int j = 0; j < 4; ++j)
                acc[i][j] = __builtin_amdgcn_mfma_f32_16x16x32_bf16(af[i], bfr[j], acc[i][j], 0, 0, 0);
        c0 = (c0 + 1 == 3) ? 0 : c0 + 1;
    }

#pragma unroll
    for (int j = 0; j < 4; ++j) {
        const int n = nbase + wn * 64 + j * 16 + lr;
        const float bias = bout[n];
#pragma unroll
        for (int i = 0; i < 2; ++i) {
#pragma unroll
            for (int r = 0; r < 4; ++r) {
                int m = mbase + wm * 32 + i * 16 + lk * 4 + r;
                out[(size_t)m * DMODEL + n] = acc[i][j][r] + bias;
            }
        }
    }
}

// ---------------- fused ReLU attention, 32x32 MFMA + LDS-staged K/V ----------------
__launch_bounds__(256, 2)
__global__ void attn_kernel(const __hip_bfloat16* __restrict__ qb,
                            const __hip_bfloat16* __restrict__ kb,
                            const __hip_bfloat16* __restrict__ vtb,
                            __hip_bfloat16* __restrict__ ao) {
    __shared__ __align__(16) char Klds[3][8192];
    __shared__ __align__(16) char Vlds[3][8192];
    const int lane = threadIdx.x & 63;
    const int wave = threadIdx.x >> 6;
    const int l32  = lane & 31;
    const int hi   = lane >> 5;

    int bid = blockIdx.x;
    bid = (bid & 7) * 64 + (bid >> 3);
    const int bh   = bid >> 4;            // 0..31  (= b*16 + h)
    const int qblk = bid & 15;            // 0..15
    const int b_ = bh >> 4, h = bh & 15;
    const int qbase = qblk * 128 + wave * 32;

    const __hip_bfloat16* __restrict__ Q = qb + (size_t)bh * SEQ * DIMH;
    const char* __restrict__ Kg = (const char*)(kb  + (size_t)bh * SEQ * DIMH);
    const char* __restrict__ Vg = (const char*)(vtb + (size_t)bh * DIMH * SEQ);

    bf16x8 qf[4];
#pragma unroll
    for (int ks = 0; ks < 4; ++ks)
        qf[ks] = *reinterpret_cast<const bf16x8*>(
            &Q[(size_t)(qbase + l32) * DIMH + ks * 16 + hi * 8]);

    f32x16 acco[2] = {};

    auto stage = [&](int buf, int t0) {
#pragma unroll
        for (int pass = 0; pass < 2; ++pass) {
            const int b   = wave * 2048 + pass * 1024 + lane * 16;
            const int row = b >> 7;
            const int cb  = (b & 127) ^ ((row & 7) << 4);
            glds16(Kg + (size_t)(t0 + row) * 128 + cb,
                   &Klds[buf][wave * 2048 + pass * 1024]);
            glds16(Vg + (size_t)row * (SEQ * 2) + t0 * 2 + cb,
                   &Vlds[buf][wave * 2048 + pass * 1024]);
        }
    };

    stage(0, 0);
    stage(1, 64);

    const int swz = (l32 & 7) << 4;
    int c0 = 0;
    for (int t0 = 0; t0 < SEQ; t0 += 64) {
        if (t0 + 64 < SEQ) WAIT_VMCNT(4); else WAIT_VMCNT(0);
        BARRIER();
        if (t0 + 128 < SEQ) {
            int sb = c0 + 2; if (sb >= 3) sb -= 3;
            stage(sb, t0 + 128);
        }
        const char* Kc = Klds[c0];
        const char* Vc = Vlds[c0];

        // ---- S^T = K Q^T ----
        f32x16 s0 = {}, s1 = {};
#pragma unroll
        for (int ks = 0; ks < 4; ++ks) {
            bf16x8 k0f = *reinterpret_cast<const bf16x8*>(
                Kc + l32 * 128        + ((ks * 32 + 16 * hi) ^ swz));
            bf16x8 k1f = *reinterpret_cast<const bf16x8*>(
                Kc + (32 + l32) * 128 + ((ks * 32 + 16 * hi) ^ swz));
            s0 = __builtin_amdgcn_mfma_f32_32x32x16_bf16(k0f, qf[ks], s0, 0, 0, 0);
            s1 = __builtin_amdgcn_mfma_f32_32x32x16_bf16(k1f, qf[ks], s1, 0, 0, 0);
        }
#pragma unroll
        for (int r = 0; r < 16; ++r) {
            s0[r] = fmaxf(s0[r], 0.f);
            s1[r] = fmaxf(s1[r], 0.f);
        }
        // ---- O += P V (lane-local P; scrambled-t V reads) ----
#pragma unroll
        for (int kt = 0; kt < 4; ++kt) {
            union { __hip_bfloat16 hh[8]; bf16x8 v; } pa;
            const int rb = (kt & 1) * 8;
#pragma unroll
            for (int j = 0; j < 8; ++j)
                pa.hh[j] = __float2bfloat16(kt < 2 ? s0[rb + j] : s1[rb + j]);
#pragma unroll
            for (int nt = 0; nt < 2; ++nt) {
                const int row = nt * 32 + l32;
                union { unsigned long long d[2]; bf16x8 v; } vb;
                vb.d[0] = *reinterpret_cast<const unsigned long long*>(
                    Vc + row * 128 + ((kt * 32 + 8 * hi) ^ swz));
                vb.d[1] = *reinterpret_cast<const unsigned long long*>(
                    Vc + row * 128 + ((kt * 32 + 16 + 8 * hi) ^ swz));
                acco[nt] = __builtin_amdgcn_mfma_f32_32x32x16_bf16(pa.v, vb.v, acco[nt], 0, 0, 0);
            }
        }
        c0 = (c0 + 1 == 3) ? 0 : c0 + 1;
    }

#pragma unroll
    for (int nt = 0; nt < 2; ++nt) {
#pragma unroll
        for (int r = 0; r < 16; ++r) {
            int q = qbase + (r & 3) + 8 * (r >> 2) + 4 * hi;
            ao[(size_t)(b_ * SEQ + q) * DMODEL + h * 64 + nt * 32 + l32] =
                __float2bfloat16(acco[nt][r]);
        }
    }
}

extern "C" void kernel_launch(void* const* d_in, const int* in_sizes, int n_in,
                              void* d_out, int out_size, void* d_ws, size_t ws_size,
                              hipStream_t stream) {
    const float* hs   = (const float*)d_in[0];
    const float* Wq   = (const float*)d_in[1];
    const float* Wkv  = (const float*)d_in[2];
    const float* Wout = (const float*)d_in[3];
    const float* bout = (const float*)d_in[4];
    float* out = (float*)d_out;

    char* ws = (char*)d_ws;
    size_t off = 0;
    auto alloc = [&](size_t bytes) { char* p = ws + off; off += bytes; return p; };
    __hip_bfloat16* hsb  = (__hip_bfloat16*)alloc((size_t)MROWS * DMODEL * 2); // dead after proj
    __hip_bfloat16* WqT  = (__hip_bfloat16*)alloc((size_t)DMODEL * DMODEL * 2);
    __hip_bfloat16* WkvT = (__hip_bfloat16*)alloc((size_t)DMODEL * DMODEL * 2);
    __hip_bfloat16* WoT  = (__hip_bfloat16*)alloc((size_t)DMODEL * DMODEL * 2);
    __hip_bfloat16* qb   = (__hip_bfloat16*)alloc((size_t)MROWS * DMODEL * 2);
    __hip_bfloat16* kb   = (__hip_bfloat16*)alloc((size_t)MROWS * DMODEL * 2);
    __hip_bfloat16* vtb  = (__hip_bfloat16*)alloc((size_t)MROWS * DMODEL * 2);
    __hip_bfloat16* ao   = hsb;  // alias: hs_bf16 is dead once attention runs

    // 1. casts / transposes
    cvt_kernel<<<(MROWS * DMODEL / 4 + 255) / 256, 256, 0, stream>>>(hs, hsb, MROWS * DMODEL / 4);
    dim3 trg(32, 32), trb(32, 32);
    tr_kernel<<<trg, trb, 0, stream>>>(Wq, WqT);
    tr_kernel<<<trg, trb, 0, stream>>>(Wkv, WkvT);
    tr_kernel<<<trg, trb, 0, stream>>>(Wout, WoT);

    // 2. fused Q/KV projection (Q pre-scaled by 1/8): 256 blocks x 512 thr
    proj_kernel<<<256, 512, 0, stream>>>(hsb, WqT, WkvT, qb, kb, vtb);

    // 3. fused relu attention
    attn_kernel<<<NBATCH * HEADS * (SEQ / 128), 256, 0, stream>>>(qb, kb, vtb, ao);

    // 4. output projection: 256 blocks x 512 thr
    outproj_kernel<<<256, 512, 0, stream>>>(ao, WoT, bout, out);
}

// Round 8
// 118.053 us; speedup vs baseline: 1.2097x; 1.0219x over previous
//
#include <hip/hip_runtime.h>
#include <hip/hip_bf16.h>

#define HEADS  16
#define DIMH   64
#define NBATCH 2
#define SEQ    2048
#define DMODEL 1024
#define MROWS  (NBATCH * SEQ)   // 4096

typedef __attribute__((ext_vector_type(8)))  short bf16x8;
typedef __attribute__((ext_vector_type(4)))  float f32x4;
typedef __attribute__((ext_vector_type(16))) float f32x16;
typedef __attribute__((ext_vector_type(4)))  float float4v;
typedef __attribute__((ext_vector_type(4)))  short short4v;

__device__ inline void glds16(const void* g, void* l) {
    __builtin_amdgcn_global_load_lds(
        (const __attribute__((address_space(1))) unsigned int*)g,
        (__attribute__((address_space(3))) unsigned int*)l, 16, 0, 0);
}

#define WAIT_VMCNT(N) asm volatile("s_waitcnt vmcnt(" #N ")" ::: "memory")
#define BARRIER() do { __builtin_amdgcn_s_barrier(); asm volatile("" ::: "memory"); } while (0)

// ---------------- f32 -> bf16 cast (4 elems/thread) ----------------
__global__ void cvt_kernel(const float* __restrict__ in,
                           __hip_bfloat16* __restrict__ out, int n4) {
    int i = blockIdx.x * blockDim.x + threadIdx.x;
    if (i >= n4) return;
    float4v v = reinterpret_cast<const float4v*>(in)[i];
    union { short4v s; __hip_bfloat16 h[4]; } u;
#pragma unroll
    for (int j = 0; j < 4; ++j) u.h[j] = __float2bfloat16(v[j]);
    reinterpret_cast<short4v*>(out)[i] = u.s;
}

// ------------- W [D][D] f32 -> WT [o][i] bf16 (transpose+cast) -------------
__global__ void tr_kernel(const float* __restrict__ W,
                          __hip_bfloat16* __restrict__ WT) {
    __shared__ float tile[32][33];
    int i = blockIdx.y * 32 + threadIdx.y;   // row of W
    int o = blockIdx.x * 32 + threadIdx.x;   // col of W
    tile[threadIdx.y][threadIdx.x] = W[i * DMODEL + o];
    __syncthreads();
    int oo = blockIdx.x * 32 + threadIdx.y;  // row of WT
    int ii = blockIdx.y * 32 + threadIdx.x;  // col of WT
    WT[oo * DMODEL + ii] = __float2bfloat16(tile[threadIdx.x][threadIdx.y]);
}

// ============ 8-wave GEMM core (BK=32, 3-buffer, counted vmcnt) ============

// ---------------- fused Q/KV projection GEMM (BM=128, BN=256) --------------
__launch_bounds__(512, 2)
__global__ void proj_kernel(const __hip_bfloat16* __restrict__ hsb,
                            const __hip_bfloat16* __restrict__ WqT,
                            const __hip_bfloat16* __restrict__ WkvT,
                            __hip_bfloat16* __restrict__ qb,
                            __hip_bfloat16* __restrict__ kb,
                            __hip_bfloat16* __restrict__ vtb) {
    __shared__ __align__(16) char SLDS[73728];
    char (*Alds)[8192]  = (char (*)[8192])SLDS;              // 3 x 8KB
    char (*Blds)[16384] = (char (*)[16384])(SLDS + 24576);   // 3 x 16KB
    char* CT = SLDS;                                         // 64KB reuse

    const int tid  = threadIdx.x;         // 0..511
    const int wave = tid >> 6;            // 0..7
    const int lane = tid & 63;
    const int lr = lane & 15;
    const int lk = lane >> 4;
    const int wm = wave >> 2, wn = wave & 3;   // 2M x 4N, wave tile 64x64

    // bijective XCD swizzle: 256 blocks, 32 contiguous ids per XCD
    int bid = blockIdx.x;
    bid = (bid & 7) * 32 + (bid >> 3);
    const int xt = bid & 7;               // n-tile of 256 (q: 0..3, kv: 4..7)
    const int mt = bid >> 3;              // m-tile 0..31
    const bool is_q = xt < 4;
    const int mbase = mt * 128;
    const int nbase = (xt & 3) * 256;
    const __hip_bfloat16* __restrict__ WT = is_q ? WqT : WkvT;

    const char* __restrict__ Ab = (const char*)(hsb + (size_t)mbase * DMODEL);
    const char* __restrict__ Bb = (const char*)(WT + (size_t)nbase * DMODEL);

    auto stage = [&](int buf, int k0) {
        const size_t colb = (size_t)k0 * 2 + lk * 16;
        glds16(Ab + (size_t)(wave * 16 + lr) * (DMODEL * 2) + colb,
               &Alds[buf][wave * 1024]);
#pragma unroll
        for (int r = 0; r < 2; ++r)
            glds16(Bb + (size_t)((r * 8 + wave) * 16 + lr) * (DMODEL * 2) + colb,
                   &Blds[buf][r * 8192 + wave * 1024]);
    };

    stage(0, 0);
    stage(1, 32);

    f32x4 acc[4][4] = {};
    int c0 = 0;
    for (int t = 0; t < DMODEL / 32; ++t) {
        if (t < DMODEL / 32 - 1) WAIT_VMCNT(3); else WAIT_VMCNT(0);
        BARRIER();
        if (t + 2 < DMODEL / 32) {
            int sb = c0 + 2; if (sb >= 3) sb -= 3;
            stage(sb, (t + 2) * 32);
        }
        bf16x8 af[4], bfr[4];
#pragma unroll
        for (int i = 0; i < 4; ++i) {
            af[i]  = *reinterpret_cast<const bf16x8*>(&Alds[c0][(wm * 4 + i) * 1024 + lane * 16]);
            bfr[i] = *reinterpret_cast<const bf16x8*>(&Blds[c0][(wn * 4 + i) * 1024 + lane * 16]);
        }
#pragma unroll
        for (int i = 0; i < 4; ++i)
#pragma unroll
            for (int j = 0; j < 4; ++j)
                acc[i][j] = __builtin_amdgcn_mfma_f32_16x16x32_bf16(af[i], bfr[j], acc[i][j], 0, 0, 0);
        c0 = (c0 + 1 == 3) ? 0 : c0 + 1;
    }

    // ================= epilogue via LDS (coalesced stores) =================
    const float qscale = is_q ? 0.125f : 1.0f;   // fold attention scale into Q
    const int b_ = mbase >> 11;
    const int s0 = mbase & (SEQ - 1);
    BARRIER();   // all waves done reading staging LDS

    // 1) acc -> CT [128m][256n] bf16, key = ((m>>2)&7)<<4
#pragma unroll
    for (int i = 0; i < 4; ++i)
#pragma unroll
        for (int j = 0; j < 4; ++j)
#pragma unroll
            for (int r = 0; r < 4; ++r) {
                int m = wm * 64 + i * 16 + lk * 4 + r;
                int n = wn * 64 + j * 16 + lr;
                *reinterpret_cast<__hip_bfloat16*>(
                    &CT[m * 512 + ((n * 2) ^ (((m >> 2) & 7) << 4))]) =
                    __float2bfloat16(acc[i][j][r] * qscale);
            }
    BARRIER();

    // 2) coalesced q/k stores: 8-lane groups write 128B head-segment runs
    __hip_bfloat16* __restrict__ dst0 = is_q ? qb : kb;
#pragma unroll
    for (int p = 0; p < 8; ++p) {
        int g = p * 64 + (tid >> 3);      // 0..511
        int m = g >> 2, seg = g & 3, o = tid & 7;
        int key = ((m >> 2) & 7) << 4;
        bf16x8 val = *reinterpret_cast<const bf16x8*>(
            &CT[m * 512 + ((seg * 128 + o * 16) ^ key)]);
        int h = (nbase >> 6) + seg;
        *reinterpret_cast<bf16x8*>(
            &dst0[(((size_t)b_ * HEADS + h) * SEQ + s0 + m) * DIMH + o * 8]) = val;
    }

    if (!is_q) {
        BARRIER();
        // 3) acc -> CT2 [256n][128m] bf16, key2 = ((n&7)<<4)
#pragma unroll
        for (int i = 0; i < 4; ++i)
#pragma unroll
            for (int j = 0; j < 4; ++j)
#pragma unroll
                for (int r = 0; r < 4; ++r) {
                    int m = wm * 64 + i * 16 + lk * 4 + r;
                    int n = wn * 64 + j * 16 + lr;
                    *reinterpret_cast<__hip_bfloat16*>(
                        &CT[n * 256 + ((m * 2) ^ ((n & 7) << 4))]) =
                        __float2bfloat16(acc[i][j][r]);
                }
        BARRIER();
        // 4) coalesced vtb stores: 8-lane groups write 128B s-runs
#pragma unroll
        for (int p = 0; p < 8; ++p) {
            int g = p * 64 + (tid >> 3);      // 0..511
            int n = g >> 1, half = g & 1, o = tid & 7;
            int key2 = (n & 7) << 4;
            bf16x8 val = *reinterpret_cast<const bf16x8*>(
                &CT[n * 256 + ((half * 128 + o * 16) ^ key2)]);
            int h = (nbase >> 6) + (n >> 6);
            int dh = n & 63;
            *reinterpret_cast<bf16x8*>(
                &vtb[(((size_t)b_ * HEADS + h) * DIMH + dh) * SEQ + s0 + half * 64 + o * 8]) = val;
        }
    }
}

// -------- output projection GEMM + bias (BM=128, BN=128, f32 out) ----------
__launch_bounds__(512, 2)
__global__ void outproj_kernel(const __hip_bfloat16* __restrict__ ao,
                               const __hip_bfloat16* __restrict__ WoT,
                               const float* __restrict__ bout,
                               float* __restrict__ out) {
    __shared__ __align__(16) char Alds[3][8192];
    __shared__ __align__(16) char Blds[3][8192];
    const int tid  = threadIdx.x;
    const int wave = tid >> 6;
    const int lane = tid & 63;
    const int lr = lane & 15;
    const int lk = lane >> 4;
    const int wm = wave >> 1, wn = wave & 1;   // 4M x 2N, wave tile 32x64

    // bijective XCD swizzle: 256 blocks, 32 contiguous ids per XCD
    int bid = blockIdx.x;
    bid = (bid & 7) * 32 + (bid >> 3);
    const int xt = bid & 7;
    const int mt = bid >> 3;
    const int mbase = mt * 128;
    const int nbase = xt * 128;

    const char* __restrict__ Ab = (const char*)(ao + (size_t)mbase * DMODEL);
    const char* __restrict__ Bb = (const char*)(WoT + (size_t)nbase * DMODEL);

    auto stage = [&](int buf, int k0) {
        const size_t colb = (size_t)k0 * 2 + lk * 16;
        glds16(Ab + (size_t)(wave * 16 + lr) * (DMODEL * 2) + colb,
               &Alds[buf][wave * 1024]);
        glds16(Bb + (size_t)(wave * 16 + lr) * (DMODEL * 2) + colb,
               &Blds[buf][wave * 1024]);
    };

    stage(0, 0);
    stage(1, 32);

    f32x4 acc[2][4] = {};
    int c0 = 0;
    for (int t = 0; t < DMODEL / 32; ++t) {
        if (t < DMODEL / 32 - 1) WAIT_VMCNT(2); else WAIT_VMCNT(0);
        BARRIER();
        if (t + 2 < DMODEL / 32) {
            int sb = c0 + 2; if (sb >= 3) sb -= 3;
            stage(sb, (t + 2) * 32);
        }
        bf16x8 af[2], bfr[4];
#pragma unroll
        for (int i = 0; i < 2; ++i)
            af[i] = *reinterpret_cast<const bf16x8*>(&Alds[c0][(wm * 2 + i) * 1024 + lane * 16]);
#pragma unroll
        for (int j = 0; j < 4; ++j)
            bfr[j] = *reinterpret_cast<const bf16x8*>(&Blds[c0][(wn * 4 + j) * 1024 + lane * 16]);
#pragma unroll
        for (int i = 0; i < 2; ++i)
#pragma unroll
            for (int j = 0; j < 4; ++j)
                acc[i][j] = __builtin_amdgcn_mfma_f32_16x16x32_bf16(af[i], bfr[j], acc[i][j], 0, 0, 0);
        c0 = (c0 + 1 == 3) ? 0 : c0 + 1;
    }

#pragma unroll
    for (int j = 0; j < 4; ++j) {
        const int n = nbase + wn * 64 + j * 16 + lr;
        const float bias = bout[n];
#pragma unroll
        for (int i = 0; i < 2; ++i) {
#pragma unroll
            for (int r = 0; r < 4; ++r) {
                int m = mbase + wm * 32 + i * 16 + lk * 4 + r;
                out[(size_t)m * DMODEL + n] = acc[i][j][r] + bias;
            }
        }
    }
}

// ------- fused ReLU attention: deferred pack+PV software pipeline ----------
// grid 512 x 4 waves; wave owns 32 q rows. 4 LDS buffers; at iter t:
// stage(t+2) -> pack S(t-1) interleaved with PV(t-1) -> QK(t) into freed regs.
__launch_bounds__(256, 2)
__global__ void attn_kernel(const __hip_bfloat16* __restrict__ qb,
                            const __hip_bfloat16* __restrict__ kb,
                            const __hip_bfloat16* __restrict__ vtb,
                            __hip_bfloat16* __restrict__ ao) {
    __shared__ __align__(16) char Klds[4][8192];
    __shared__ __align__(16) char Vlds[4][8192];
    const int lane = threadIdx.x & 63;
    const int wave = threadIdx.x >> 6;
    const int l32  = lane & 31;
    const int hi   = lane >> 5;

    int bid = blockIdx.x;
    bid = (bid & 7) * 64 + (bid >> 3);
    const int bh   = bid >> 4;            // 0..31  (= b*16 + h)
    const int qblk = bid & 15;            // 0..15
    const int b_ = bh >> 4, h = bh & 15;
    const int qbase = qblk * 128 + wave * 32;

    const __hip_bfloat16* __restrict__ Q = qb + (size_t)bh * SEQ * DIMH;
    const char* __restrict__ Kg = (const char*)(kb  + (size_t)bh * SEQ * DIMH);
    const char* __restrict__ Vg = (const char*)(vtb + (size_t)bh * DIMH * SEQ);

    bf16x8 qf[4];
#pragma unroll
    for (int ks = 0; ks < 4; ++ks)
        qf[ks] = *reinterpret_cast<const bf16x8*>(
            &Q[(size_t)(qbase + l32) * DIMH + ks * 16 + hi * 8]);

    auto stage = [&](int buf, int t0) {
#pragma unroll
        for (int pass = 0; pass < 2; ++pass) {
            const int b   = wave * 2048 + pass * 1024 + lane * 16;
            const int row = b >> 7;
            const int cb  = (b & 127) ^ ((row & 7) << 4);
            glds16(Kg + (size_t)(t0 + row) * 128 + cb,
                   &Klds[buf][wave * 2048 + pass * 1024]);
            glds16(Vg + (size_t)row * (SEQ * 2) + t0 * 2 + cb,
                   &Vlds[buf][wave * 2048 + pass * 1024]);
        }
    };

    const int swz = (l32 & 7) << 4;
    f32x16 acco[2] = {};
    f32x16 sp0, sp1;     // S of previous tile, lives across iterations

    auto do_qk = [&](const char* Kc) {
        sp0 = f32x16{}; sp1 = f32x16{};
        __builtin_amdgcn_s_setprio(1);
#pragma unroll
        for (int ks = 0; ks < 4; ++ks) {
            bf16x8 k0f = *reinterpret_cast<const bf16x8*>(
                Kc + l32 * 128        + ((ks * 32 + 16 * hi) ^ swz));
            bf16x8 k1f = *reinterpret_cast<const bf16x8*>(
                Kc + (32 + l32) * 128 + ((ks * 32 + 16 * hi) ^ swz));
            sp0 = __builtin_amdgcn_mfma_f32_32x32x16_bf16(k0f, qf[ks], sp0, 0, 0, 0);
            sp1 = __builtin_amdgcn_mfma_f32_32x32x16_bf16(k1f, qf[ks], sp1, 0, 0, 0);
        }
        __builtin_amdgcn_s_setprio(0);
    };

    // relu+pack of S(prev) interleaved per-kt with PV MFMAs (pack VALU
    // overlaps PV MFMA; S(prev) is ~1 iteration old -> no result stall)
    auto do_packpv = [&](const char* Vc) {
        __builtin_amdgcn_s_setprio(1);
#pragma unroll
        for (int kt = 0; kt < 4; ++kt) {
            union { __hip_bfloat16 hh[8]; bf16x8 v; } pa;
            const int rb = (kt & 1) * 8;
#pragma unroll
            for (int j = 0; j < 8; ++j) {
                float x = (kt < 2) ? sp0[rb + j] : sp1[rb + j];
                pa.hh[j] = __float2bfloat16(fmaxf(x, 0.f));
            }
#pragma unroll
            for (int nt = 0; nt < 2; ++nt) {
                const int row = nt * 32 + l32;
                union { unsigned long long d[2]; bf16x8 v; } vb;
                vb.d[0] = *reinterpret_cast<const unsigned long long*>(
                    Vc + row * 128 + ((kt * 32 + 8 * hi) ^ swz));
                vb.d[1] = *reinterpret_cast<const unsigned long long*>(
                    Vc + row * 128 + ((kt * 32 + 16 + 8 * hi) ^ swz));
                acco[nt] = __builtin_amdgcn_mfma_f32_32x32x16_bf16(pa.v, vb.v, acco[nt], 0, 0, 0);
            }
        }
        __builtin_amdgcn_s_setprio(0);
    };

    stage(0, 0);
    stage(1, 64);

    // iteration 0: QK only
    WAIT_VMCNT(4);
    BARRIER();
    stage(2, 128);
    do_qk(Klds[0]);

    for (int t = 1; t < SEQ / 64; ++t) {
        if (t < SEQ / 64 - 1) WAIT_VMCNT(4); else WAIT_VMCNT(0);
        BARRIER();
        if (t + 2 < SEQ / 64) stage((t + 2) & 3, (t + 2) * 64);
        do_packpv(Vlds[(t - 1) & 3]);   // PV of tile t-1 (buffer never == stage target)
        do_qk(Klds[t & 3]);             // QK of tile t into freed S regs
    }
    do_packpv(Vlds[(SEQ / 64 - 1) & 3]);

    // ---- epilogue: C row q = (r&3)+8*(r>>2)+4*hi, col dh = nt*32+l32 ----
#pragma unroll
    for (int nt = 0; nt < 2; ++nt) {
#pragma unroll
        for (int r = 0; r < 16; ++r) {
            int q = qbase + (r & 3) + 8 * (r >> 2) + 4 * hi;
            ao[(size_t)(b_ * SEQ + q) * DMODEL + h * 64 + nt * 32 + l32] =
                __float2bfloat16(acco[nt][r]);
        }
    }
}

extern "C" void kernel_launch(void* const* d_in, const int* in_sizes, int n_in,
                              void* d_out, int out_size, void* d_ws, size_t ws_size,
                              hipStream_t stream) {
    const float* hs   = (const float*)d_in[0];
    const float* Wq   = (const float*)d_in[1];
    const float* Wkv  = (const float*)d_in[2];
    const float* Wout = (const float*)d_in[3];
    const float* bout = (const float*)d_in[4];
    float* out = (float*)d_out;

    char* ws = (char*)d_ws;
    size_t off = 0;
    auto alloc = [&](size_t bytes) { char* p = ws + off; off += bytes; return p; };
    __hip_bfloat16* hsb  = (__hip_bfloat16*)alloc((size_t)MROWS * DMODEL * 2); // dead after proj
    __hip_bfloat16* WqT  = (__hip_bfloat16*)alloc((size_t)DMODEL * DMODEL * 2);
    __hip_bfloat16* WkvT = (__hip_bfloat16*)alloc((size_t)DMODEL * DMODEL * 2);
    __hip_bfloat16* WoT  = (__hip_bfloat16*)alloc((size_t)DMODEL * DMODEL * 2);
    __hip_bfloat16* qb   = (__hip_bfloat16*)alloc((size_t)MROWS * DMODEL * 2);
    __hip_bfloat16* kb   = (__hip_bfloat16*)alloc((size_t)MROWS * DMODEL * 2);
    __hip_bfloat16* vtb  = (__hip_bfloat16*)alloc((size_t)MROWS * DMODEL * 2);
    __hip_bfloat16* ao   = hsb;  // alias: hs_bf16 is dead once attention runs

    // 1. casts / transposes
    cvt_kernel<<<(MROWS * DMODEL / 4 + 255) / 256, 256, 0, stream>>>(hs, hsb, MROWS * DMODEL / 4);
    dim3 trg(32, 32), trb(32, 32);
    tr_kernel<<<trg, trb, 0, stream>>>(Wq, WqT);
    tr_kernel<<<trg, trb, 0, stream>>>(Wkv, WkvT);
    tr_kernel<<<trg, trb, 0, stream>>>(Wout, WoT);

    // 2. fused Q/KV projection (Q pre-scaled by 1/8): 256 blocks x 512 thr
    proj_kernel<<<256, 512, 0, stream>>>(hsb, WqT, WkvT, qb, kb, vtb);

    // 3. fused relu attention
    attn_kernel<<<NBATCH * HEADS * (SEQ / 128), 256, 0, stream>>>(qb, kb, vtb, ao);

    // 4. output projection: 256 blocks x 512 thr
    outproj_kernel<<<256, 512, 0, stream>>>(ao, WoT, bout, out);
}